// Round 3
// baseline (428.832 us; speedup 1.0000x reference)
//
#include <hip/hip_runtime.h>
#include <stdint.h>

// out[b][o] = clamp((sum_k x[b][k]*W[o][k] + t[o]) >> (-n[o]), act_min[o], act_max[o])
// B=8192, IN=4096, OUT=4096. x,W arrive int32; harness reads d_out as int32.

#define BDIM 8192
#define INDIM 4096
#define OUTDIM 4096

typedef __attribute__((ext_vector_type(4))) int I4;

// ---------------- pack: int32 -> int8, both arrays, 16 ints/thread ----------------
__global__ __launch_bounds__(256) void pack_both(const int* __restrict__ x,
                                                 const int* __restrict__ W,
                                                 uint32_t* __restrict__ xp,
                                                 uint32_t* __restrict__ wp) {
    const size_t xq = (size_t)BDIM * INDIM / 16;   // uint4 outputs for x: 2097152
    size_t idx = (size_t)blockIdx.x * 256 + threadIdx.x;
    const int* src;
    uint32_t* dst;
    if (idx < xq) {
        src = x + idx * 16;
        dst = xp + idx * 4;
    } else {
        size_t j = idx - xq;
        src = W + j * 16;
        dst = wp + j * 4;
    }
    uint32_t outw[4];
#pragma unroll
    for (int q = 0; q < 4; ++q) {
        int4 a = ((const int4*)src)[q];
        outw[q] = ((uint32_t)a.x & 255u)
                | (((uint32_t)a.y & 255u) << 8)
                | (((uint32_t)a.z & 255u) << 16)
                | (((uint32_t)a.w & 255u) << 24);
    }
    *(uint4*)dst = *(uint4*)outw;
}

// ---------------- GEMM: 128x128 tile, BK=128, mfma_i32_16x16x64_i8 ----------------
// m97 staging (global_load_lds width=16) with XOR-swizzled LDS layout implemented
// via per-lane global addresses (LDS scatter is fixed at lane*16).
// LDS element (row, k16) lives at row*128 + (k16 ^ (row&7))*16.
// 32 MFMA per barrier-pair (AITER cadence), 32 K-iterations total.
__global__ __launch_bounds__(256) void gemm_i8_fused(
    const uint8_t* __restrict__ Xp,   // [BDIM][INDIM] int8
    const uint8_t* __restrict__ Wp,   // [OUTDIM][INDIM] int8
    const int* __restrict__ t, const int* __restrict__ nsh,
    const int* __restrict__ amin, const int* __restrict__ amax,
    int* __restrict__ out) {

    __shared__ uint8_t sA[128 * 128];  // 16 KB
    __shared__ uint8_t sB[128 * 128];  // 16 KB

    const int bn = blockIdx.x;            // 0..31  (OUT tiles)
    const int bm = blockIdx.y;            // 0..63  (batch tiles)
    const int tid = threadIdx.x;
    const int w = tid >> 6;               // wave 0..3
    const int lane = tid & 63;
    const int wm = (w & 1) * 64;
    const int wn = (w >> 1) * 64;

    // staging: chunk = 1024B = 8 rows x 128B. Wave w stages chunks r*4+w, r=0..3.
    const int lrow8 = lane >> 3;                 // 0..7 row-in-chunk
    const int gk16 = (lane & 7) ^ lrow8;         // swizzled 16B-segment index
    const int gcol = gk16 * 16;

    const uint8_t* gA0 = Xp + (size_t)(bm * 128) * INDIM;
    const uint8_t* gB0 = Wp + (size_t)(bn * 128) * INDIM;

    I4 acc[4][4];
#pragma unroll
    for (int i = 0; i < 4; ++i)
#pragma unroll
        for (int j = 0; j < 4; ++j) acc[i][j] = (I4){0, 0, 0, 0};

    const int quad = lane >> 4;           // 0..3
    const int rl = lane & 15;
    const int swz = rl & 7;               // row&7 for all fragment rows this lane reads

    for (int k0 = 0; k0 < INDIM; k0 += 128) {
#pragma unroll
        for (int r = 0; r < 4; ++r) {
            const int c = r * 4 + w;              // chunk 0..15
            const int row = c * 8 + lrow8;        // tile row 0..127
            __builtin_amdgcn_global_load_lds(
                (const __attribute__((address_space(1))) uint32_t*)(gA0 + (size_t)row * INDIM + k0 + gcol),
                (__attribute__((address_space(3))) uint32_t*)(sA + c * 1024 + lane * 16),
                16, 0, 0);
            __builtin_amdgcn_global_load_lds(
                (const __attribute__((address_space(1))) uint32_t*)(gB0 + (size_t)row * INDIM + k0 + gcol),
                (__attribute__((address_space(3))) uint32_t*)(sB + c * 1024 + lane * 16),
                16, 0, 0);
        }
        __syncthreads();

#pragma unroll
        for (int s = 0; s < 2; ++s) {
            const int koff = ((s * 4 + quad) ^ swz) * 16;   // swizzled k-segment
            I4 af[4], bf[4];
#pragma unroll
            for (int i = 0; i < 4; ++i)
                af[i] = *(const I4*)(sA + (wm + i * 16 + rl) * 128 + koff);
#pragma unroll
            for (int j = 0; j < 4; ++j)
                bf[j] = *(const I4*)(sB + (wn + j * 16 + rl) * 128 + koff);

#pragma unroll
            for (int i = 0; i < 4; ++i)
#pragma unroll
                for (int j = 0; j < 4; ++j)
                    acc[i][j] = __builtin_amdgcn_mfma_i32_16x16x64_i8(af[i], bf[j], acc[i][j], 0, 0, 0);
        }
        __syncthreads();
    }

    // epilogue: C/D layout col=lane&15, row=(lane>>4)*4+reg
#pragma unroll
    for (int j = 0; j < 4; ++j) {
        const int o = bn * 128 + wn + j * 16 + rl;
        const int tt = t[o];
        const int sh = -nsh[o];
        const int mn = amin[o];
        const int mx = amax[o];
#pragma unroll
        for (int i = 0; i < 4; ++i) {
            const int rowbase = bm * 128 + wm + i * 16 + quad * 4;
#pragma unroll
            for (int r = 0; r < 4; ++r) {
                int v = acc[i][j][r] + tt;
                v >>= sh;
                v = v < mn ? mn : (v > mx ? mx : v);
                __builtin_nontemporal_store(v, &out[(size_t)(rowbase + r) * OUTDIM + o]);
            }
        }
    }
}

extern "C" void kernel_launch(void* const* d_in, const int* in_sizes, int n_in,
                              void* d_out, int out_size, void* d_ws, size_t ws_size,
                              hipStream_t stream) {
    const int* x = (const int*)d_in[0];       // [8192][4096]
    const int* W = (const int*)d_in[1];       // [4096][4096]
    const int* t = (const int*)d_in[2];       // [4096]
    const int* n = (const int*)d_in[3];       // [4096]
    const int* amin = (const int*)d_in[4];    // [4096]
    const int* amax = (const int*)d_in[5];    // [4096]
    int* out = (int*)d_out;

    uint8_t* xp = (uint8_t*)d_ws;                              // 33554432 B
    uint8_t* wp = xp + (size_t)BDIM * INDIM;                   // 16777216 B

    {
        // (8192*4096 + 4096*4096)/16 ints per uint4-thread = 3145728 threads
        int nthreads = (BDIM * (INDIM / 16)) + (OUTDIM * (INDIM / 16));
        pack_both<<<nthreads / 256, 256, 0, stream>>>(x, W, (uint32_t*)xp, (uint32_t*)wp);
    }

    dim3 grid(OUTDIM / 128, BDIM / 128);  // (32, 64)
    gemm_i8_fused<<<grid, 256, 0, stream>>>(xp, wp, t, n, amin, amax, out);
}

// Round 4
// 417.618 us; speedup vs baseline: 1.0269x; 1.0269x over previous
//
#include <hip/hip_runtime.h>
#include <stdint.h>

// out[b][o] = clamp((sum_k x[b][k]*W[o][k] + t[o]) >> (-n[o]), act_min[o], act_max[o])
// B=8192, IN=4096, OUT=4096. x,W arrive int32; harness reads d_out as int32.
//
// R4 structure: barrier-free "flat" GEMM. Pack pass writes x,W in MFMA fragment
// order; GEMM loads fragments straight from global (global_load_dwordx4), register
// double-buffered, zero LDS, zero __syncthreads in the K-loop.

#define BDIM 8192
#define INDIM 4096
#define OUTDIM 4096

typedef __attribute__((ext_vector_type(4))) int I4;

// ---------------- pack: int32 -> int8 in fragment order ----------------
// Xpk[(m16*64 + kb)*1024 + lane*16 + b] = x[m16*16 + (lane&15)][kb*64 + (lane>>4)*16 + b]
// (identical mapping to the verified R2/R3 LDS fragment layout)
__global__ __launch_bounds__(256) void pack_frag(const int* __restrict__ x,
                                                 const int* __restrict__ W,
                                                 uint32_t* __restrict__ xp,
                                                 uint32_t* __restrict__ wp) {
    const uint32_t xq = (BDIM / 16) * 64 * 64;   // 2097152 x-threads
    uint32_t u = blockIdx.x * 256 + threadIdx.x;
    const int* src;
    uint32_t* dst;
    if (u < xq) {
        uint32_t m16 = u >> 12, kb = (u >> 6) & 63, lane = u & 63;
        src = x + (size_t)(m16 * 16 + (lane & 15)) * INDIM + kb * 64 + (lane >> 4) * 16;
        dst = xp + (size_t)u * 4;
    } else {
        uint32_t v = u - xq;
        uint32_t n16 = v >> 12, kb = (v >> 6) & 63, lane = v & 63;
        src = W + (size_t)(n16 * 16 + (lane & 15)) * INDIM + kb * 64 + (lane >> 4) * 16;
        dst = wp + (size_t)v * 4;
    }
    uint32_t ow[4];
#pragma unroll
    for (int q = 0; q < 4; ++q) {
        int4 a = ((const int4*)src)[q];
        ow[q] = ((uint32_t)a.x & 255u)
              | (((uint32_t)a.y & 255u) << 8)
              | (((uint32_t)a.z & 255u) << 16)
              | (((uint32_t)a.w & 255u) << 24);
    }
    *(uint4*)dst = *(uint4*)ow;
}

// ---------------- flat GEMM: no LDS, no barriers ----------------
// Block 128x128 (4 waves, 64x64 quadrants). Per wave per k-step (K=64):
// 4 A-frag + 4 B-frag global_load_dwordx4 + 16 mfma_i32_16x16x64_i8.
// Register double-buffer: set0/set1 alternate, prefetch distance = 16 MFMAs.
__global__ __launch_bounds__(256) void gemm_flat(
    const uint8_t* __restrict__ Xp,   // fragment-ordered, 512*64*1024 B
    const uint8_t* __restrict__ Wp,   // fragment-ordered, 256*64*1024 B
    const int* __restrict__ t, const int* __restrict__ nsh,
    const int* __restrict__ amin, const int* __restrict__ amax,
    int* __restrict__ out) {

    const int bn = blockIdx.x;            // 0..31
    const int bm = blockIdx.y;            // 0..63
    const int tid = threadIdx.x;
    const int w = tid >> 6;
    const int lane = tid & 63;
    const int wm = (w & 1) * 64;
    const int wn = (w >> 1) * 64;
    const int quad = lane >> 4;
    const int rl = lane & 15;

    const uint8_t* pa[4];
    const uint8_t* pb[4];
#pragma unroll
    for (int i = 0; i < 4; ++i)
        pa[i] = Xp + ((size_t)(bm * 8 + (w & 1) * 4 + i) << 16) + lane * 16;
#pragma unroll
    for (int j = 0; j < 4; ++j)
        pb[j] = Wp + ((size_t)(bn * 8 + (w >> 1) * 4 + j) << 16) + lane * 16;

    I4 acc[4][4];
#pragma unroll
    for (int i = 0; i < 4; ++i)
#pragma unroll
        for (int j = 0; j < 4; ++j) acc[i][j] = (I4){0, 0, 0, 0};

    I4 a0[4], b0[4], a1[4], b1[4];
#pragma unroll
    for (int i = 0; i < 4; ++i) a0[i] = *(const I4*)(pa[i]);
#pragma unroll
    for (int j = 0; j < 4; ++j) b0[j] = *(const I4*)(pb[j]);
#pragma unroll
    for (int i = 0; i < 4; ++i) a1[i] = *(const I4*)(pa[i] + 1024);
#pragma unroll
    for (int j = 0; j < 4; ++j) b1[j] = *(const I4*)(pb[j] + 1024);

    for (int kb = 0; kb < 62; kb += 2) {
        // MFMA on set0 (@kb), then refill set0 (@kb+2)
#pragma unroll
        for (int i = 0; i < 4; ++i)
#pragma unroll
            for (int j = 0; j < 4; ++j)
                acc[i][j] = __builtin_amdgcn_mfma_i32_16x16x64_i8(a0[i], b0[j], acc[i][j], 0, 0, 0);
        const size_t o0 = (size_t)(kb + 2) * 1024;
#pragma unroll
        for (int i = 0; i < 4; ++i) a0[i] = *(const I4*)(pa[i] + o0);
#pragma unroll
        for (int j = 0; j < 4; ++j) b0[j] = *(const I4*)(pb[j] + o0);

        // MFMA on set1 (@kb+1), then refill set1 (@kb+3)
#pragma unroll
        for (int i = 0; i < 4; ++i)
#pragma unroll
            for (int j = 0; j < 4; ++j)
                acc[i][j] = __builtin_amdgcn_mfma_i32_16x16x64_i8(a1[i], b1[j], acc[i][j], 0, 0, 0);
        const size_t o1 = (size_t)(kb + 3) * 1024;
#pragma unroll
        for (int i = 0; i < 4; ++i) a1[i] = *(const I4*)(pa[i] + o1);
#pragma unroll
        for (int j = 0; j < 4; ++j) b1[j] = *(const I4*)(pb[j] + o1);

        // phase-lock the block's 4 waves for L1 fragment sharing (no memory drain)
        __builtin_amdgcn_s_barrier();
    }
    // kb=62 (set0) and kb=63 (set1), already loaded
#pragma unroll
    for (int i = 0; i < 4; ++i)
#pragma unroll
        for (int j = 0; j < 4; ++j)
            acc[i][j] = __builtin_amdgcn_mfma_i32_16x16x64_i8(a0[i], b0[j], acc[i][j], 0, 0, 0);
#pragma unroll
    for (int i = 0; i < 4; ++i)
#pragma unroll
        for (int j = 0; j < 4; ++j)
            acc[i][j] = __builtin_amdgcn_mfma_i32_16x16x64_i8(a1[i], b1[j], acc[i][j], 0, 0, 0);

    // epilogue: C/D layout col=lane&15, row=(lane>>4)*4+reg (verified R2)
#pragma unroll
    for (int j = 0; j < 4; ++j) {
        const int o = bn * 128 + wn + j * 16 + rl;
        const int tt = t[o];
        const int sh = -nsh[o];
        const int mn = amin[o];
        const int mx = amax[o];
#pragma unroll
        for (int i = 0; i < 4; ++i) {
            const int rowbase = bm * 128 + wm + i * 16 + quad * 4;
#pragma unroll
            for (int r = 0; r < 4; ++r) {
                int v = acc[i][j][r] + tt;
                v >>= sh;
                v = v < mn ? mn : (v > mx ? mx : v);
                __builtin_nontemporal_store(v, &out[(size_t)(rowbase + r) * OUTDIM + o]);
            }
        }
    }
}

extern "C" void kernel_launch(void* const* d_in, const int* in_sizes, int n_in,
                              void* d_out, int out_size, void* d_ws, size_t ws_size,
                              hipStream_t stream) {
    const int* x = (const int*)d_in[0];
    const int* W = (const int*)d_in[1];
    const int* t = (const int*)d_in[2];
    const int* n = (const int*)d_in[3];
    const int* amin = (const int*)d_in[4];
    const int* amax = (const int*)d_in[5];
    int* out = (int*)d_out;

    uint8_t* xp = (uint8_t*)d_ws;                    // 33554432 B (fragment order)
    uint8_t* wp = xp + (size_t)BDIM * INDIM;         // 16777216 B (fragment order)

    {
        int nthreads = (BDIM / 16) * 64 * 64 + (OUTDIM / 16) * 64 * 64;  // 3145728
        pack_frag<<<nthreads / 256, 256, 0, stream>>>(x, W, (uint32_t*)xp, (uint32_t*)wp);
    }

    dim3 grid(OUTDIM / 128, BDIM / 128);  // (32, 64)
    gemm_flat<<<grid, 256, 0, stream>>>(xp, wp, t, n, amin, amax, out);
}